// Round 8
// baseline (203.089 us; speedup 1.0000x reference)
//
#include <hip/hip_runtime.h>
#include <hip/hip_bf16.h>
#include <stdint.h>

#define TTOK 1024
#define CDIM 1024
#define NEXP 8
#define IDIM 1024
#define TWOI 2048
#define NSLOT 2048

typedef float f32x4 __attribute__((ext_vector_type(4)));
typedef short s16x8 __attribute__((ext_vector_type(8)));
typedef unsigned short u16;
typedef u16 u16x4 __attribute__((ext_vector_type(4)));
typedef u16 u16x8 __attribute__((ext_vector_type(8)));

__device__ __forceinline__ u16 f2bf(float f) {
  unsigned x = __float_as_uint(f);
  x += 0x7fffu + ((x >> 16) & 1u);
  return (u16)(x >> 16);
}

__device__ __forceinline__ void gload_lds16(const void* g, void* l) {
  __builtin_amdgcn_global_load_lds(
      (const __attribute__((address_space(1))) void*)g,
      (__attribute__((address_space(3))) void*)l, 16, 0, 0);
}

// ---------------- router: logits -> softmax -> top2; also emits bf16 x ----------------
__global__ __launch_bounds__(64) void router_k(const float* __restrict__ x,
                                               const float* __restrict__ rw,
                                               float* __restrict__ topw,
                                               int* __restrict__ topidx,
                                               u16* __restrict__ xb) {
  const int t = blockIdx.x;
  const int lane = threadIdx.x;
  float p[NEXP];
#pragma unroll
  for (int e = 0; e < NEXP; ++e) p[e] = 0.f;
  const float* xr = x + (size_t)t * CDIM;
  u16* xbr = xb + (size_t)t * CDIM;
  for (int c0 = lane * 4; c0 < CDIM; c0 += 64 * 4) {
    f32x4 xv = *(const f32x4*)(xr + c0);
    u16x4 xc;
#pragma unroll
    for (int q = 0; q < 4; ++q) xc[q] = f2bf(xv[q]);
    *(u16x4*)(xbr + c0) = xc;   // fused fp32->bf16 cast of x
#pragma unroll
    for (int e = 0; e < NEXP; ++e) {
      f32x4 wv = *(const f32x4*)(rw + (size_t)e * CDIM + c0);
      p[e] += xv[0] * wv[0] + xv[1] * wv[1] + xv[2] * wv[2] + xv[3] * wv[3];
    }
  }
#pragma unroll
  for (int e = 0; e < NEXP; ++e) {
    float v = p[e];
#pragma unroll
    for (int off = 32; off >= 1; off >>= 1) v += __shfl_xor(v, off);
    p[e] = v;
  }
  if (lane == 0) {
    float m = p[0];
#pragma unroll
    for (int e = 1; e < NEXP; ++e) m = fmaxf(m, p[e]);
    float pe[NEXP];
    float den = 0.f;
#pragma unroll
    for (int e = 0; e < NEXP; ++e) { pe[e] = __expf(p[e] - m); den += pe[e]; }
    int i0 = 0;
#pragma unroll
    for (int e = 1; e < NEXP; ++e) if (p[e] > p[i0]) i0 = e;
    int i1 = (i0 == 0) ? 1 : 0;
#pragma unroll
    for (int e = 0; e < NEXP; ++e) if (e != i0 && p[e] > p[i1]) i1 = e;
    const float inv = 1.f / den;
    topw[t * 2] = pe[i0] * inv;
    topw[t * 2 + 1] = pe[i1] * inv;
    topidx[t * 2] = i0;
    topidx[t * 2 + 1] = i1;
  }
}

// ---------------- build: histogram + prefix + scatter (one block) ----------------
__global__ __launch_bounds__(1024) void build_k(const int* __restrict__ topidx,
                                                const float* __restrict__ topw,
                                                int* __restrict__ meta,
                                                int* __restrict__ slot_token,
                                                float* __restrict__ gatew) {
  __shared__ int cnt[NEXP], off[NEXP], cur[NEXP];
  const int t = threadIdx.x;
  if (t < NEXP) { cnt[t] = 0; cur[t] = 0; }
  __syncthreads();
  const int e0 = topidx[t * 2];
  const int e1 = topidx[t * 2 + 1];
  atomicAdd(&cnt[e0], 1);
  atomicAdd(&cnt[e1], 1);
  __syncthreads();
  if (t == 0) {
    int acc = 0;
    for (int e = 0; e < NEXP; ++e) { off[e] = acc; acc += cnt[e]; }
  }
  __syncthreads();
  if (t < NEXP) { meta[t] = cnt[t]; meta[16 + t] = off[t]; }
  {
    const int p0 = atomicAdd(&cur[e0], 1);
    const int s0 = off[e0] + p0;
    slot_token[s0] = t;
    gatew[s0] = topw[t * 2];
    const int p1 = atomicAdd(&cur[e1], 1);
    const int s1 = off[e1] + p1;
    slot_token[s1] = t;
    gatew[s1] = topw[t * 2 + 1];
  }
}

// ---------------- GEMM1 + fused swiglu ----------------
// Block computes 64 interleaved h-columns: block-col c even -> w_in row i0+(c>>1)
// (gate), odd -> I+i0+(c>>1) (up), i0 = blockIdx.x*32. Epilogue pairs g/u via
// __shfl_xor(v,1) and stores bf16 a[slot, i0+(c>>1)] from even lanes.
__global__ __launch_bounds__(256) void gemm1_k(const u16* __restrict__ A,
                                               const float* __restrict__ W,
                                               const float* __restrict__ b_in,
                                               u16* __restrict__ Aout,
                                               const int* __restrict__ meta,
                                               const int* __restrict__ slot_token) {
  constexpr int BM = 64, K = CDIM;
  const int e = blockIdx.z;
  const int cnt = meta[e];
  const int m0 = blockIdx.y * BM;
  if (m0 >= cnt) return;
  const int off = meta[16 + e];
  const int i0 = blockIdx.x * 32;

  __shared__ u16 sA[2][BM * 64];
  __shared__ u16 sB[2][64 * 64];

  const int tid = threadIdx.x;
  const int lane = tid & 63;
  const int w = tid >> 6;
  const int wr = w >> 1;
  const int wc = w & 1;

  // A staging (gathered rows, pre-swizzled source; linear LDS dest).
  const u16* aSrc[2];
  int aDst[2];
#pragma unroll
  for (int i = 0; i < 2; ++i) {
    const int r = w * 16 + i * 8 + (lane >> 3);
    int rr = m0 + r;
    if (rr > cnt - 1) rr = cnt - 1;
    const int rowg = slot_token[off + rr];
    const int cs = (lane & 7) ^ (r & 7);
    aSrc[i] = A + (size_t)rowg * K + cs * 8;
    aDst[i] = (w * 16 + i * 8) * 64 + lane * 8;
  }

  // B staging: block-col brow = tid>>2; k-quarter bq = tid&3; fp32->bf16.
  const int brow = tid >> 2;
  const int bq = tid & 3;
  const int wrow = (brow & 1) ? (IDIM + i0 + (brow >> 1)) : (i0 + (brow >> 1));
  const float* bSrc = W + ((size_t)e * TWOI + wrow) * K + bq * 16;
  const int brow7 = brow & 7;
  const int bOff0 = brow * 64 + (((bq * 2) ^ brow7) * 8);
  const int bOff1 = brow * 64 + (((bq * 2 + 1) ^ brow7) * 8);

  f32x4 acc[2][2];
#pragma unroll
  for (int m = 0; m < 2; ++m)
#pragma unroll
    for (int n = 0; n < 2; ++n) acc[m][n] = (f32x4){0.f, 0.f, 0.f, 0.f};

  // prologue: stage step 0 into buffer 0
  {
#pragma unroll
    for (int i = 0; i < 2; ++i) gload_lds16(aSrc[i], &sA[0][aDst[i]]);
    f32x4 v0 = *(const f32x4*)(bSrc);
    f32x4 v1 = *(const f32x4*)(bSrc + 4);
    f32x4 v2 = *(const f32x4*)(bSrc + 8);
    f32x4 v3 = *(const f32x4*)(bSrc + 12);
    u16x8 lo, hi;
#pragma unroll
    for (int q = 0; q < 4; ++q) lo[q] = f2bf(v0[q]);
#pragma unroll
    for (int q = 0; q < 4; ++q) lo[4 + q] = f2bf(v1[q]);
#pragma unroll
    for (int q = 0; q < 4; ++q) hi[q] = f2bf(v2[q]);
#pragma unroll
    for (int q = 0; q < 4; ++q) hi[4 + q] = f2bf(v3[q]);
    *(u16x8*)(&sB[0][bOff0]) = lo;
    *(u16x8*)(&sB[0][bOff1]) = hi;
  }
  __syncthreads();

  int c = 0;
  for (int k0 = 0; k0 < K; k0 += 64) {
    const int nk = k0 + 64;
    const bool has_next = nk < K;
    f32x4 v0, v1, v2, v3;
    if (has_next) {
#pragma unroll
      for (int i = 0; i < 2; ++i) gload_lds16(aSrc[i] + nk, &sA[1 - c][aDst[i]]);
      const float* bs = bSrc + nk;
      v0 = *(const f32x4*)(bs);
      v1 = *(const f32x4*)(bs + 4);
      v2 = *(const f32x4*)(bs + 8);
      v3 = *(const f32x4*)(bs + 12);
    }
#pragma unroll
    for (int kh = 0; kh < 2; ++kh) {
      const int j = kh * 4 + (lane >> 4);
      s16x8 af[2], bf[2];
#pragma unroll
      for (int m = 0; m < 2; ++m) {
        const int r = wr * 32 + m * 16 + (lane & 15);
        af[m] = *(const s16x8*)(&sA[c][r * 64 + ((j ^ (r & 7)) * 8)]);
      }
#pragma unroll
      for (int n = 0; n < 2; ++n) {
        const int r = wc * 32 + n * 16 + (lane & 15);
        bf[n] = *(const s16x8*)(&sB[c][r * 64 + ((j ^ (r & 7)) * 8)]);
      }
#pragma unroll
      for (int m = 0; m < 2; ++m)
#pragma unroll
        for (int n = 0; n < 2; ++n)
          acc[m][n] = __builtin_amdgcn_mfma_f32_16x16x32_bf16(af[m], bf[n], acc[m][n], 0, 0, 0);
    }
    if (has_next) {
      u16x8 lo, hi;
#pragma unroll
      for (int q = 0; q < 4; ++q) lo[q] = f2bf(v0[q]);
#pragma unroll
      for (int q = 0; q < 4; ++q) lo[4 + q] = f2bf(v1[q]);
#pragma unroll
      for (int q = 0; q < 4; ++q) hi[q] = f2bf(v2[q]);
#pragma unroll
      for (int q = 0; q < 4; ++q) hi[4 + q] = f2bf(v3[q]);
      *(u16x8*)(&sB[1 - c][bOff0]) = lo;
      *(u16x8*)(&sB[1 - c][bOff1]) = hi;
    }
    __syncthreads();
    c ^= 1;
  }

  // fused swiglu epilogue. col c = wc*32 + n*16 + (lane&15); parity = lane&1.
#pragma unroll
  for (int m = 0; m < 2; ++m) {
#pragma unroll
    for (int jj = 0; jj < 4; ++jj) {
      const int tr = wr * 32 + m * 16 + ((lane >> 4) * 4) + jj;
      const bool live = (m0 + tr) < cnt;
      const size_t slot = (size_t)(off + m0 + tr);
#pragma unroll
      for (int n = 0; n < 2; ++n) {
        const int cc = wc * 32 + n * 16 + (lane & 15);
        const int wrow_c = (cc & 1) ? (IDIM + i0 + (cc >> 1)) : (i0 + (cc >> 1));
        float v = acc[m][n][jj] + b_in[(size_t)e * TWOI + wrow_c];
        const float vo = __shfl_xor(v, 1);
        if (!(lane & 1) && live) {
          const float g = v, u = vo;
          const float aval = (g / (1.f + __expf(-g))) * u;
          Aout[slot * IDIM + i0 + (cc >> 1)] = f2bf(aval);
        }
      }
    }
  }
}

// ---------------- GEMM2 + fused combine (atomic scatter to out) ----------------
__global__ __launch_bounds__(256) void gemm2_k(const u16* __restrict__ A,
                                               const float* __restrict__ W,
                                               const float* __restrict__ b_out,
                                               float* __restrict__ out,
                                               const int* __restrict__ meta,
                                               const int* __restrict__ slot_token,
                                               const float* __restrict__ gatew) {
  constexpr int BM = 64, K = IDIM;
  const int e = blockIdx.z;
  const int cnt = meta[e];
  const int m0 = blockIdx.y * BM;
  if (m0 >= cnt) return;
  const int off = meta[16 + e];
  const int n0 = blockIdx.x * 64;

  __shared__ u16 sA[2][BM * 64];
  __shared__ u16 sB[2][64 * 64];

  const int tid = threadIdx.x;
  const int lane = tid & 63;
  const int w = tid >> 6;
  const int wr = w >> 1;
  const int wc = w & 1;

  const u16* aSrc[2];
  int aDst[2];
#pragma unroll
  for (int i = 0; i < 2; ++i) {
    const int r = w * 16 + i * 8 + (lane >> 3);
    int rr = m0 + r;
    if (rr > cnt - 1) rr = cnt - 1;
    const int cs = (lane & 7) ^ (r & 7);
    aSrc[i] = A + (size_t)(off + rr) * K + cs * 8;
    aDst[i] = (w * 16 + i * 8) * 64 + lane * 8;
  }

  const int brow = tid >> 2;
  const int bq = tid & 3;
  const float* bSrc = W + ((size_t)e * CDIM + (n0 + brow)) * K + bq * 16;
  const int brow7 = brow & 7;
  const int bOff0 = brow * 64 + (((bq * 2) ^ brow7) * 8);
  const int bOff1 = brow * 64 + (((bq * 2 + 1) ^ brow7) * 8);

  f32x4 acc[2][2];
#pragma unroll
  for (int m = 0; m < 2; ++m)
#pragma unroll
    for (int n = 0; n < 2; ++n) acc[m][n] = (f32x4){0.f, 0.f, 0.f, 0.f};

  {
#pragma unroll
    for (int i = 0; i < 2; ++i) gload_lds16(aSrc[i], &sA[0][aDst[i]]);
    f32x4 v0 = *(const f32x4*)(bSrc);
    f32x4 v1 = *(const f32x4*)(bSrc + 4);
    f32x4 v2 = *(const f32x4*)(bSrc + 8);
    f32x4 v3 = *(const f32x4*)(bSrc + 12);
    u16x8 lo, hi;
#pragma unroll
    for (int q = 0; q < 4; ++q) lo[q] = f2bf(v0[q]);
#pragma unroll
    for (int q = 0; q < 4; ++q) lo[4 + q] = f2bf(v1[q]);
#pragma unroll
    for (int q = 0; q < 4; ++q) hi[q] = f2bf(v2[q]);
#pragma unroll
    for (int q = 0; q < 4; ++q) hi[4 + q] = f2bf(v3[q]);
    *(u16x8*)(&sB[0][bOff0]) = lo;
    *(u16x8*)(&sB[0][bOff1]) = hi;
  }
  __syncthreads();

  int c = 0;
  for (int k0 = 0; k0 < K; k0 += 64) {
    const int nk = k0 + 64;
    const bool has_next = nk < K;
    f32x4 v0, v1, v2, v3;
    if (has_next) {
#pragma unroll
      for (int i = 0; i < 2; ++i) gload_lds16(aSrc[i] + nk, &sA[1 - c][aDst[i]]);
      const float* bs = bSrc + nk;
      v0 = *(const f32x4*)(bs);
      v1 = *(const f32x4*)(bs + 4);
      v2 = *(const f32x4*)(bs + 8);
      v3 = *(const f32x4*)(bs + 12);
    }
#pragma unroll
    for (int kh = 0; kh < 2; ++kh) {
      const int j = kh * 4 + (lane >> 4);
      s16x8 af[2], bf[2];
#pragma unroll
      for (int m = 0; m < 2; ++m) {
        const int r = wr * 32 + m * 16 + (lane & 15);
        af[m] = *(const s16x8*)(&sA[c][r * 64 + ((j ^ (r & 7)) * 8)]);
      }
#pragma unroll
      for (int n = 0; n < 2; ++n) {
        const int r = wc * 32 + n * 16 + (lane & 15);
        bf[n] = *(const s16x8*)(&sB[c][r * 64 + ((j ^ (r & 7)) * 8)]);
      }
#pragma unroll
      for (int m = 0; m < 2; ++m)
#pragma unroll
        for (int n = 0; n < 2; ++n)
          acc[m][n] = __builtin_amdgcn_mfma_f32_16x16x32_bf16(af[m], bf[n], acc[m][n], 0, 0, 0);
    }
    if (has_next) {
      u16x8 lo, hi;
#pragma unroll
      for (int q = 0; q < 4; ++q) lo[q] = f2bf(v0[q]);
#pragma unroll
      for (int q = 0; q < 4; ++q) lo[4 + q] = f2bf(v1[q]);
#pragma unroll
      for (int q = 0; q < 4; ++q) hi[q] = f2bf(v2[q]);
#pragma unroll
      for (int q = 0; q < 4; ++q) hi[4 + q] = f2bf(v3[q]);
      *(u16x8*)(&sB[1 - c][bOff0]) = lo;
      *(u16x8*)(&sB[1 - c][bOff1]) = hi;
    }
    __syncthreads();
    c ^= 1;
  }

  // fused combine epilogue: out[token, col] += gatew[slot] * (v + bias)
#pragma unroll
  for (int m = 0; m < 2; ++m) {
#pragma unroll
    for (int jj = 0; jj < 4; ++jj) {
      const int tr = wr * 32 + m * 16 + ((lane >> 4) * 4) + jj;
      if (m0 + tr < cnt) {
        const int slot = off + m0 + tr;
        const int tok = slot_token[slot];
        const float gw = gatew[slot];
#pragma unroll
        for (int n = 0; n < 2; ++n) {
          const int col = n0 + wc * 32 + n * 16 + (lane & 15);
          const float v = acc[m][n][jj] + b_out[(size_t)e * CDIM + col];
          atomicAdd(&out[(size_t)tok * CDIM + col], gw * v);
        }
      }
    }
  }
}

extern "C" void kernel_launch(void* const* d_in, const int* in_sizes, int n_in,
                              void* d_out, int out_size, void* d_ws, size_t ws_size,
                              hipStream_t stream) {
  const float* x = (const float*)d_in[0];
  const float* rw = (const float*)d_in[1];
  const float* w_in = (const float*)d_in[2];
  const float* b_in = (const float*)d_in[3];
  const float* w_out = (const float*)d_in[4];
  const float* b_out = (const float*)d_in[5];
  float* out = (float*)d_out;
  char* ws = (char*)d_ws;

  // ws layout (bytes)
  int* meta = (int*)ws;                               // counts@0, offsets@16
  int* slot_token = (int*)(ws + 1024);                // 2048 ints
  float* topw = (float*)(ws + 1024 + 8192);           // 2048 f32
  int* topidx = (int*)(ws + 1024 + 16384);            // 2048 ints
  float* gatew = (float*)(ws + 1024 + 24576);         // 2048 f32
  u16* xb = (u16*)(ws + 65536);                       // 1M bf16 = 2MB
  u16* a = (u16*)(ws + 65536 + (2u << 20));           // 2M bf16 = 4MB

  hipMemsetAsync(out, 0, (size_t)TTOK * CDIM * sizeof(float), stream);
  router_k<<<TTOK, 64, 0, stream>>>(x, rw, topw, topidx, xb);
  build_k<<<1, 1024, 0, stream>>>(topidx, topw, meta, slot_token, gatew);
  // GEMM1+swiglu: 32 col-tiles (32 a-cols each), worst-case 32 m-tiles, 8 experts.
  gemm1_k<<<dim3(32, 32, NEXP), 256, 0, stream>>>(
      xb, w_in, b_in, a, meta, slot_token);
  // GEMM2+combine: 16 col-tiles (64 cols), worst-case 32 m-tiles, 8 experts.
  gemm2_k<<<dim3(16, 32, NEXP), 256, 0, stream>>>(
      a, w_out, b_out, out, meta, slot_token, gatew);
}

// Round 10
// 192.754 us; speedup vs baseline: 1.0536x; 1.0536x over previous
//
#include <hip/hip_runtime.h>
#include <hip/hip_bf16.h>
#include <stdint.h>

#define TTOK 1024
#define CDIM 1024
#define NEXP 8
#define IDIM 1024
#define TWOI 2048
#define NSLOT 2048
#define NSTEP 16  // K/64 for both GEMMs

typedef float f32x4 __attribute__((ext_vector_type(4)));
typedef short s16x8 __attribute__((ext_vector_type(8)));
typedef unsigned short u16;
typedef u16 u16x4 __attribute__((ext_vector_type(4)));
typedef u16 u16x8 __attribute__((ext_vector_type(8)));

#define VMCNT(n) asm volatile("s_waitcnt vmcnt(" #n ")" ::: "memory")
#define SBAR() __builtin_amdgcn_s_barrier()
#define SCHED0() __builtin_amdgcn_sched_barrier(0)

__device__ __forceinline__ u16 f2bf(float f) {
  unsigned x = __float_as_uint(f);
  x += 0x7fffu + ((x >> 16) & 1u);
  return (u16)(x >> 16);
}

__device__ __forceinline__ void gload_lds16(const void* g, void* l) {
  __builtin_amdgcn_global_load_lds(
      (const __attribute__((address_space(1))) void*)g,
      (__attribute__((address_space(3))) void*)l, 16, 0, 0);
}

// ---------------- weight fp32 -> bf16 pre-convert (one pass) ----------------
__global__ __launch_bounds__(256) void cvtw_k(const float* __restrict__ win,
                                              const float* __restrict__ wout,
                                              u16* __restrict__ bin,
                                              u16* __restrict__ bout) {
  const int NIN = NEXP * TWOI * CDIM;           // 16,777,216
  const int NTOT = NIN + NEXP * CDIM * IDIM;    // 25,165,824
  for (int i = (blockIdx.x * 256 + threadIdx.x) * 8; i < NTOT;
       i += gridDim.x * 256 * 8) {
    const float* src;
    u16* dst;
    int j;
    if (i < NIN) { src = win; dst = bin; j = i; }
    else         { src = wout; dst = bout; j = i - NIN; }
    f32x4 v0 = *(const f32x4*)(src + j);
    f32x4 v1 = *(const f32x4*)(src + j + 4);
    u16x8 o;
#pragma unroll
    for (int q = 0; q < 4; ++q) o[q] = f2bf(v0[q]);
#pragma unroll
    for (int q = 0; q < 4; ++q) o[4 + q] = f2bf(v1[q]);
    *(u16x8*)(dst + j) = o;
  }
}

// ---------------- router: logits -> softmax -> top2; also emits bf16 x ----------------
__global__ __launch_bounds__(64) void router_k(const float* __restrict__ x,
                                               const float* __restrict__ rw,
                                               float* __restrict__ topw,
                                               int* __restrict__ topidx,
                                               u16* __restrict__ xb) {
  const int t = blockIdx.x;
  const int lane = threadIdx.x;
  float p[NEXP];
#pragma unroll
  for (int e = 0; e < NEXP; ++e) p[e] = 0.f;
  const float* xr = x + (size_t)t * CDIM;
  u16* xbr = xb + (size_t)t * CDIM;
  for (int c0 = lane * 4; c0 < CDIM; c0 += 64 * 4) {
    f32x4 xv = *(const f32x4*)(xr + c0);
    u16x4 xc;
#pragma unroll
    for (int q = 0; q < 4; ++q) xc[q] = f2bf(xv[q]);
    *(u16x4*)(xbr + c0) = xc;
#pragma unroll
    for (int e = 0; e < NEXP; ++e) {
      f32x4 wv = *(const f32x4*)(rw + (size_t)e * CDIM + c0);
      p[e] += xv[0] * wv[0] + xv[1] * wv[1] + xv[2] * wv[2] + xv[3] * wv[3];
    }
  }
#pragma unroll
  for (int e = 0; e < NEXP; ++e) {
    float v = p[e];
#pragma unroll
    for (int off = 32; off >= 1; off >>= 1) v += __shfl_xor(v, off);
    p[e] = v;
  }
  if (lane == 0) {
    float m = p[0];
#pragma unroll
    for (int e = 1; e < NEXP; ++e) m = fmaxf(m, p[e]);
    float pe[NEXP];
    float den = 0.f;
#pragma unroll
    for (int e = 0; e < NEXP; ++e) { pe[e] = __expf(p[e] - m); den += pe[e]; }
    int i0 = 0;
#pragma unroll
    for (int e = 1; e < NEXP; ++e) if (p[e] > p[i0]) i0 = e;
    int i1 = (i0 == 0) ? 1 : 0;
#pragma unroll
    for (int e = 0; e < NEXP; ++e) if (e != i0 && p[e] > p[i1]) i1 = e;
    const float inv = 1.f / den;
    topw[t * 2] = pe[i0] * inv;
    topw[t * 2 + 1] = pe[i1] * inv;
    topidx[t * 2] = i0;
    topidx[t * 2 + 1] = i1;
  }
}

// ---------------- build: histogram + prefix + scatter (one block) ----------------
__global__ __launch_bounds__(1024) void build_k(const int* __restrict__ topidx,
                                                const float* __restrict__ topw,
                                                int* __restrict__ meta,
                                                int* __restrict__ slot_token,
                                                float* __restrict__ gatew) {
  __shared__ int cnt[NEXP], off[NEXP], cur[NEXP];
  const int t = threadIdx.x;
  if (t < NEXP) { cnt[t] = 0; cur[t] = 0; }
  __syncthreads();
  const int e0 = topidx[t * 2];
  const int e1 = topidx[t * 2 + 1];
  atomicAdd(&cnt[e0], 1);
  atomicAdd(&cnt[e1], 1);
  __syncthreads();
  if (t == 0) {
    int acc = 0;
    for (int e = 0; e < NEXP; ++e) { off[e] = acc; acc += cnt[e]; }
  }
  __syncthreads();
  if (t < NEXP) { meta[t] = cnt[t]; meta[16 + t] = off[t]; }
  {
    const int p0 = atomicAdd(&cur[e0], 1);
    const int s0 = off[e0] + p0;
    slot_token[s0] = t;
    gatew[s0] = topw[t * 2];
    const int p1 = atomicAdd(&cur[e1], 1);
    const int s1 = off[e1] + p1;
    slot_token[s1] = t;
    gatew[s1] = topw[t * 2 + 1];
  }
}

// ---------------- GEMM1 + fused swiglu; bf16 A and B, 3-deep ring, counted vmcnt ----------------
// BM=128, BN=64 (interleaved gate/up cols). 6 gload_lds per wave per step.
__global__ __launch_bounds__(256) void gemm1_k(const u16* __restrict__ A,
                                               const u16* __restrict__ Wb,
                                               const float* __restrict__ b_in,
                                               u16* __restrict__ Aout,
                                               const int* __restrict__ meta,
                                               const int* __restrict__ slot_token) {
  constexpr int BM = 128, K = CDIM;
  const int e = blockIdx.z;
  const int cnt = meta[e];
  const int m0 = blockIdx.y * BM;
  if (m0 >= cnt) return;
  const int off = meta[16 + e];
  const int i0 = blockIdx.x * 32;

  __shared__ u16 sA[3][BM * 64];
  __shared__ u16 sB[3][64 * 64];

  const int tid = threadIdx.x;
  const int lane = tid & 63;
  const int w = tid >> 6;
  const int wr = w >> 1;
  const int wc = w & 1;

  // A staging sources (gathered rows; pre-swizzled chunk; linear LDS dest).
  const u16* aSrc[4];
  int aDst[4];
#pragma unroll
  for (int i = 0; i < 4; ++i) {
    const int r = w * 32 + i * 8 + (lane >> 3);
    int rr = m0 + r;
    if (rr > cnt - 1) rr = cnt - 1;
    const int rowg = slot_token[off + rr];
    const int cs = (lane & 7) ^ (r & 7);
    aSrc[i] = A + (size_t)rowg * K + cs * 8;
    aDst[i] = (w * 32 + i * 8) * 64 + lane * 8;
  }
  // B staging sources: block-col r -> w_in row (interleaved gate/up).
  const u16* bSrc[2];
  int bDst[2];
#pragma unroll
  for (int i = 0; i < 2; ++i) {
    const int r = w * 16 + i * 8 + (lane >> 3);
    const int wrow = (r & 1) ? (IDIM + i0 + (r >> 1)) : (i0 + (r >> 1));
    const int cs = (lane & 7) ^ (r & 7);
    bSrc[i] = Wb + ((size_t)e * TWOI + wrow) * K + cs * 8;
    bDst[i] = (w * 16 + i * 8) * 64 + lane * 8;
  }

  f32x4 acc[4][2];
#pragma unroll
  for (int m = 0; m < 4; ++m)
#pragma unroll
    for (int n = 0; n < 2; ++n) acc[m][n] = (f32x4){0.f, 0.f, 0.f, 0.f};

  auto STAGE = [&](int t) {
    const int cb = t % 3;
    const int ko = t * 64;
#pragma unroll
    for (int i = 0; i < 4; ++i) gload_lds16(aSrc[i] + ko, &sA[cb][aDst[i]]);
#pragma unroll
    for (int i = 0; i < 2; ++i) gload_lds16(bSrc[i] + ko, &sB[cb][bDst[i]]);
  };
  auto COMPUTE = [&](int cb) {
#pragma unroll
    for (int kh = 0; kh < 2; ++kh) {
      const int j = kh * 4 + (lane >> 4);
      s16x8 af[4], bf[2];
#pragma unroll
      for (int m = 0; m < 4; ++m) {
        const int r = wr * 64 + m * 16 + (lane & 15);
        af[m] = *(const s16x8*)(&sA[cb][r * 64 + ((j ^ (r & 7)) * 8)]);
      }
#pragma unroll
      for (int n = 0; n < 2; ++n) {
        const int r = wc * 32 + n * 16 + (lane & 15);
        bf[n] = *(const s16x8*)(&sB[cb][r * 64 + ((j ^ (r & 7)) * 8)]);
      }
#pragma unroll
      for (int m = 0; m < 4; ++m)
#pragma unroll
        for (int n = 0; n < 2; ++n)
          acc[m][n] = __builtin_amdgcn_mfma_f32_16x16x32_bf16(af[m], bf[n], acc[m][n], 0, 0, 0);
    }
  };

  STAGE(0);
  STAGE(1);
  for (int t = 0; t < NSTEP - 2; ++t) {
    STAGE(t + 2);
    VMCNT(12); SCHED0();
    SBAR();
    COMPUTE(t % 3);
    SBAR();
  }
  VMCNT(6); SCHED0(); SBAR(); COMPUTE((NSTEP - 2) % 3); SBAR();
  VMCNT(0); SCHED0(); SBAR(); COMPUTE((NSTEP - 1) % 3);

  // fused swiglu epilogue: pair g/u via shfl_xor(1); even lanes store bf16 a.
#pragma unroll
  for (int m = 0; m < 4; ++m) {
#pragma unroll
    for (int jj = 0; jj < 4; ++jj) {
      const int tr = wr * 64 + m * 16 + ((lane >> 4) * 4) + jj;
      const bool live = (m0 + tr) < cnt;
      const size_t slot = (size_t)(off + m0 + tr);
#pragma unroll
      for (int n = 0; n < 2; ++n) {
        const int cc = wc * 32 + n * 16 + (lane & 15);
        const int wrow_c = (cc & 1) ? (IDIM + i0 + (cc >> 1)) : (i0 + (cc >> 1));
        float v = acc[m][n][jj] + b_in[(size_t)e * TWOI + wrow_c];
        const float vo = __shfl_xor(v, 1);
        if (!(lane & 1) && live) {
          const float g = v, u = vo;
          const float aval = (g / (1.f + __expf(-g))) * u;
          Aout[slot * IDIM + i0 + (cc >> 1)] = f2bf(aval);
        }
      }
    }
  }
}

// ---------------- GEMM2 + fused combine; bf16 A and B, 3-deep ring ----------------
// BM=64, BN=64. 4 gload_lds per wave per step.
__global__ __launch_bounds__(256) void gemm2_k(const u16* __restrict__ A,
                                               const u16* __restrict__ Wb,
                                               const float* __restrict__ b_out,
                                               float* __restrict__ out,
                                               const int* __restrict__ meta,
                                               const int* __restrict__ slot_token,
                                               const float* __restrict__ gatew) {
  constexpr int BM = 64, K = IDIM;
  const int e = blockIdx.z;
  const int cnt = meta[e];
  const int m0 = blockIdx.y * BM;
  if (m0 >= cnt) return;
  const int off = meta[16 + e];
  const int n0 = blockIdx.x * 64;

  __shared__ u16 sA[3][BM * 64];
  __shared__ u16 sB[3][64 * 64];

  const int tid = threadIdx.x;
  const int lane = tid & 63;
  const int w = tid >> 6;
  const int wr = w >> 1;
  const int wc = w & 1;

  const u16* aSrc[2];
  int aDst[2];
#pragma unroll
  for (int i = 0; i < 2; ++i) {
    const int r = w * 16 + i * 8 + (lane >> 3);
    int rr = m0 + r;
    if (rr > cnt - 1) rr = cnt - 1;
    const int cs = (lane & 7) ^ (r & 7);
    aSrc[i] = A + (size_t)(off + rr) * K + cs * 8;
    aDst[i] = (w * 16 + i * 8) * 64 + lane * 8;
  }
  const u16* bSrc[2];
  int bDst[2];
#pragma unroll
  for (int i = 0; i < 2; ++i) {
    const int r = w * 16 + i * 8 + (lane >> 3);
    const int cs = (lane & 7) ^ (r & 7);
    bSrc[i] = Wb + ((size_t)e * CDIM + (n0 + r)) * K + cs * 8;
    bDst[i] = (w * 16 + i * 8) * 64 + lane * 8;
  }

  f32x4 acc[2][2];
#pragma unroll
  for (int m = 0; m < 2; ++m)
#pragma unroll
    for (int n = 0; n < 2; ++n) acc[m][n] = (f32x4){0.f, 0.f, 0.f, 0.f};

  auto STAGE = [&](int t) {
    const int cb = t % 3;
    const int ko = t * 64;
#pragma unroll
    for (int i = 0; i < 2; ++i) gload_lds16(aSrc[i] + ko, &sA[cb][aDst[i]]);
#pragma unroll
    for (int i = 0; i < 2; ++i) gload_lds16(bSrc[i] + ko, &sB[cb][bDst[i]]);
  };
  auto COMPUTE = [&](int cb) {
#pragma unroll
    for (int kh = 0; kh < 2; ++kh) {
      const int j = kh * 4 + (lane >> 4);
      s16x8 af[2], bf[2];
#pragma unroll
      for (int m = 0; m < 2; ++m) {
        const int r = wr * 32 + m * 16 + (lane & 15);
        af[m] = *(const s16x8*)(&sA[cb][r * 64 + ((j ^ (r & 7)) * 8)]);
      }
#pragma unroll
      for (int n = 0; n < 2; ++n) {
        const int r = wc * 32 + n * 16 + (lane & 15);
        bf[n] = *(const s16x8*)(&sB[cb][r * 64 + ((j ^ (r & 7)) * 8)]);
      }
#pragma unroll
      for (int m = 0; m < 2; ++m)
#pragma unroll
        for (int n = 0; n < 2; ++n)
          acc[m][n] = __builtin_amdgcn_mfma_f32_16x16x32_bf16(af[m], bf[n], acc[m][n], 0, 0, 0);
    }
  };

  STAGE(0);
  STAGE(1);
  for (int t = 0; t < NSTEP - 2; ++t) {
    STAGE(t + 2);
    VMCNT(8); SCHED0();
    SBAR();
    COMPUTE(t % 3);
    SBAR();
  }
  VMCNT(4); SCHED0(); SBAR(); COMPUTE((NSTEP - 2) % 3); SBAR();
  VMCNT(0); SCHED0(); SBAR(); COMPUTE((NSTEP - 1) % 3);

  // fused combine epilogue: out[token, col] += gatew[slot] * (v + bias)
#pragma unroll
  for (int m = 0; m < 2; ++m) {
#pragma unroll
    for (int jj = 0; jj < 4; ++jj) {
      const int tr = wr * 32 + m * 16 + ((lane >> 4) * 4) + jj;
      if (m0 + tr < cnt) {
        const int slot = off + m0 + tr;
        const int tok = slot_token[slot];
        const float gw = gatew[slot];
#pragma unroll
        for (int n = 0; n < 2; ++n) {
          const int col = n0 + wc * 32 + n * 16 + (lane & 15);
          const float v = acc[m][n][jj] + b_out[(size_t)e * CDIM + col];
          atomicAdd(&out[(size_t)tok * CDIM + col], gw * v);
        }
      }
    }
  }
}

extern "C" void kernel_launch(void* const* d_in, const int* in_sizes, int n_in,
                              void* d_out, int out_size, void* d_ws, size_t ws_size,
                              hipStream_t stream) {
  const float* x = (const float*)d_in[0];
  const float* rw = (const float*)d_in[1];
  const float* w_in = (const float*)d_in[2];
  const float* b_in = (const float*)d_in[3];
  const float* w_out = (const float*)d_in[4];
  const float* b_out = (const float*)d_in[5];
  float* out = (float*)d_out;
  char* ws = (char*)d_ws;

  // ws layout (bytes)
  int* meta = (int*)ws;                               // counts@0, offsets@16
  int* slot_token = (int*)(ws + 1024);                // 2048 ints
  float* topw = (float*)(ws + 1024 + 8192);           // 2048 f32
  int* topidx = (int*)(ws + 1024 + 16384);            // 2048 ints
  float* gatew = (float*)(ws + 1024 + 24576);         // 2048 f32
  u16* xb = (u16*)(ws + 65536);                       // 2 MB
  u16* a = (u16*)(ws + 65536 + (2u << 20));           // 4 MB
  u16* wbin = (u16*)(ws + 65536 + (6u << 20));        // 32 MB bf16 w_in
  u16* wbout = (u16*)(ws + 65536 + (38u << 20));      // 16 MB bf16 w_out

  hipMemsetAsync(out, 0, (size_t)TTOK * CDIM * sizeof(float), stream);
  cvtw_k<<<2048, 256, 0, stream>>>(w_in, w_out, wbin, wbout);
  router_k<<<TTOK, 64, 0, stream>>>(x, rw, topw, topidx, xb);
  build_k<<<1, 1024, 0, stream>>>(topidx, topw, meta, slot_token, gatew);
  gemm1_k<<<dim3(32, 16, NEXP), 256, 0, stream>>>(
      xb, wbin, b_in, a, meta, slot_token);
  gemm2_k<<<dim3(16, 32, NEXP), 256, 0, stream>>>(
      a, wbout, b_out, out, meta, slot_token, gatew);
}